// Round 1
// baseline (193.623 us; speedup 1.0000x reference)
//
#include <hip/hip_runtime.h>
#include <math.h>

#define HIDDEN 1024
#define SEQ 32768

__device__ __forceinline__ float dot4(float4 a, float4 h, float acc) {
    acc = fmaf(a.x, h.x, acc);
    acc = fmaf(a.y, h.y, acc);
    acc = fmaf(a.z, h.z, acc);
    acc = fmaf(a.w, h.w, acc);
    return acc;
}

// 2 rows per 64-lane wave. `hidden` is hoisted into 4 float4 registers (reused
// for both rows), and all 8 enc float4 loads are issued before any compute so
// each wave keeps 8 HBM requests in flight (vs 4 before). VGPRs ~56 -> still
// 8 waves/SIMD. Wave count halves: 16384 waves total.
__global__ __launch_bounds__(256) void energies_kernel(
    const float* __restrict__ hidden,
    const float* __restrict__ enc,
    float* __restrict__ energies) {
    const int lane = threadIdx.x & 63;
    const int wave = threadIdx.x >> 6;
    const int row0 = blockIdx.x * 8 + wave * 2;   // each wave: rows row0, row0+1

    const float4* __restrict__ hp = (const float4*)hidden;
    const float4 h0 = hp[lane];
    const float4 h1 = hp[lane + 64];
    const float4 h2 = hp[lane + 128];
    const float4 h3 = hp[lane + 192];

    const float4* __restrict__ r0 = (const float4*)(enc + (size_t)row0 * HIDDEN);
    const float4* __restrict__ r1 = (const float4*)(enc + ((size_t)row0 + 1) * HIDDEN);

    // Issue all 8 independent 16B loads before the dependent FMAs.
    const float4 a0 = r0[lane];
    const float4 a1 = r0[lane + 64];
    const float4 a2 = r0[lane + 128];
    const float4 a3 = r0[lane + 192];
    const float4 b0 = r1[lane];
    const float4 b1 = r1[lane + 64];
    const float4 b2 = r1[lane + 128];
    const float4 b3 = r1[lane + 192];

    float accA = 0.f, accB = 0.f;
    accA = dot4(a0, h0, accA);
    accA = dot4(a1, h1, accA);
    accA = dot4(a2, h2, accA);
    accA = dot4(a3, h3, accA);
    accB = dot4(b0, h0, accB);
    accB = dot4(b1, h1, accB);
    accB = dot4(b2, h2, accB);
    accB = dot4(b3, h3, accB);

#pragma unroll
    for (int off = 32; off > 0; off >>= 1) {
        accA += __shfl_xor(accA, off, 64);
        accB += __shfl_xor(accB, off, 64);
    }
    if (lane == 0) {
        energies[row0]     = accA;
        energies[row0 + 1] = accB;
    }
}

// Single block, 1024 threads; 32 energies/thread held in registers as 8 float4.
// float4 global access (8 vector loads / 8 vector stores instead of 32 scalar).
__global__ __launch_bounds__(1024) void softmax_kernel(float* __restrict__ buf) {
    __shared__ float red[16];
    const int tid  = threadIdx.x;
    const int lane = tid & 63;
    const int wv   = tid >> 6;
    float4* __restrict__ buf4 = (float4*)buf;

    float4 e[8];
    float m = -INFINITY;
#pragma unroll
    for (int i = 0; i < 8; ++i) {
        e[i] = buf4[tid + i * 1024];
        m = fmaxf(m, fmaxf(fmaxf(e[i].x, e[i].y), fmaxf(e[i].z, e[i].w)));
    }
#pragma unroll
    for (int off = 32; off > 0; off >>= 1)
        m = fmaxf(m, __shfl_down(m, off, 64));
    if (lane == 0) red[wv] = m;
    __syncthreads();
    if (tid < 16) {
        float v = red[tid];
#pragma unroll
        for (int off = 8; off > 0; off >>= 1)
            v = fmaxf(v, __shfl_down(v, off, 64));
        if (tid == 0) red[0] = v;
    }
    __syncthreads();
    m = red[0];
    __syncthreads();  // everyone has read red[0] before it is overwritten below

    float s = 0.f;
#pragma unroll
    for (int i = 0; i < 8; ++i) {
        e[i].x = __expf(e[i].x - m);
        e[i].y = __expf(e[i].y - m);
        e[i].z = __expf(e[i].z - m);
        e[i].w = __expf(e[i].w - m);
        s += (e[i].x + e[i].y) + (e[i].z + e[i].w);
    }
#pragma unroll
    for (int off = 32; off > 0; off >>= 1)
        s += __shfl_down(s, off, 64);
    if (lane == 0) red[wv] = s;
    __syncthreads();
    if (tid < 16) {
        float v = red[tid];
#pragma unroll
        for (int off = 8; off > 0; off >>= 1)
            v += __shfl_down(v, off, 64);
        if (tid == 0) red[0] = v;
    }
    __syncthreads();
    const float inv = 1.f / red[0];
#pragma unroll
    for (int i = 0; i < 8; ++i) {
        e[i].x *= inv; e[i].y *= inv; e[i].z *= inv; e[i].w *= inv;
        buf4[tid + i * 1024] = e[i];
    }
}

extern "C" void kernel_launch(void* const* d_in, const int* in_sizes, int n_in,
                              void* d_out, int out_size, void* d_ws, size_t ws_size,
                              hipStream_t stream) {
    const float* hidden = (const float*)d_in[0];           // [1024]
    const float* enc    = (const float*)d_in[1];           // [32768, 1024]
    float* out = (float*)d_out;                            // [32768] == energies staging

    energies_kernel<<<SEQ / 8, 256, 0, stream>>>(hidden, enc, out);
    softmax_kernel<<<1, 1024, 0, stream>>>(out);
}